// Round 7
// baseline (465.048 us; speedup 1.0000x reference)
//
#include <hip/hip_runtime.h>
#include <hip/hip_bf16.h>
#include <stdint.h>

typedef __attribute__((ext_vector_type(4))) float f32x4;
typedef __attribute__((ext_vector_type(8))) short short8v;

typedef __attribute__((address_space(1))) void gvoid;
typedef __attribute__((address_space(3))) void lvoid;

#define GLD16(gp, lp) __builtin_amdgcn_global_load_lds((const gvoid*)(gp), (lvoid*)(lp), 16, 0, 0)

__device__ __forceinline__ unsigned short f2bf(float f) {
    union { float ff; unsigned uu; } a; a.ff = f;
    unsigned u = a.uu;
    u += 0x7FFFu + ((u >> 16) & 1u);   // RNE; inputs finite
    return (unsigned short)(u >> 16);
}

// ---- Ub[o][r] = bf16(U[o][r] * (S[r]+eps[r])), row-major [4096][4096] ----
__global__ __launch_bounds__(256) void prep_u_kernel(
    const float* __restrict__ U, const float* __restrict__ S,
    const float* __restrict__ eps, unsigned short* __restrict__ Ub) {
    long idx = ((long)blockIdx.x * 256 + threadIdx.x) * 8;
    int r = (int)(idx & 4095);
    f32x4 u0 = *(const f32x4*)(U + idx);
    f32x4 u1 = *(const f32x4*)(U + idx + 4);
    f32x4 s0 = *(const f32x4*)(S + r);
    f32x4 s1 = *(const f32x4*)(S + r + 4);
    f32x4 e0 = *(const f32x4*)(eps + r);
    f32x4 e1 = *(const f32x4*)(eps + r + 4);
    union { uint4 v; unsigned short s[8]; } o;
#pragma unroll
    for (int j = 0; j < 4; ++j) {
        o.s[j]     = f2bf(u0[j] * (s0[j] + e0[j]));
        o.s[j + 4] = f2bf(u1[j] * (s1[j] + e1[j]));
    }
    *(uint4*)(Ub + idx) = o.v;
}

// ---- generic fp32 -> bf16 convert, 8 elems/thread ----
__global__ __launch_bounds__(256) void cvt_bf16_kernel(
    const float* __restrict__ src, unsigned short* __restrict__ dst) {
    long idx = ((long)blockIdx.x * 256 + threadIdx.x) * 8;
    f32x4 v0 = *(const f32x4*)(src + idx);
    f32x4 v1 = *(const f32x4*)(src + idx + 4);
    union { uint4 v; unsigned short s[8]; } o;
#pragma unroll
    for (int j = 0; j < 4; ++j) {
        o.s[j]     = f2bf(v0[j]);
        o.s[j + 4] = f2bf(v1[j]);
    }
    *(uint4*)(dst + idx) = o.v;
}

// ---- VtT[k][r] = bf16(Vt[r][k]); 64x64 tiles, padded LDS (conflict-free) ----
__global__ __launch_bounds__(256) void transpose_cvt_kernel(
    const float* __restrict__ src, unsigned short* __restrict__ dst) {
    __shared__ float tile[64][65];
    int tx = threadIdx.x & 63;
    int tq = threadIdx.x >> 6;
    int r0 = blockIdx.y << 6;
    int k0 = blockIdx.x << 6;
#pragma unroll
    for (int i = 0; i < 16; ++i) {
        int row = (i << 2) + tq;
        tile[row][tx] = src[(long)(r0 + row) * 4096 + k0 + tx];
    }
    __syncthreads();
#pragma unroll
    for (int i = 0; i < 16; ++i) {
        int krow = (i << 2) + tq;
        dst[(long)(k0 + krow) * 4096 + r0 + tx] = f2bf(tile[tx][krow]);
    }
}

// =====================================================================
// 256x256-tile 8-phase NT GEMM, ds_reads PIPELINED ONE PHASE AHEAD.
// C[M][N] = A[M][K] * B[N][K]^T (+bias). bf16 in, fp32 acc.
// 512 thr = 8 waves (2M x 4N), wave tile 128x64, BK=64, dbuf LDS ring
// (unchanged from round 3: [256][32] chunks, XOR slot^=(row>>1)&3 both
// sides, 0 measured conflicts).
//
// CHANGE vs round 6: cluster c's fragment ds_reads are issued in phase
// c-1 into double register sets (aR[2],bR[2]); the explicit lgkmcnt(0)
// wall is REMOVED -> compiler emits counted lgkmcnt before first use,
// so phase c-1's MFMA covers the LDS drain of cluster c's reads
// (previously serial: drain ~500cy + MFMA ~515cy per phase).
// Hazard ring (re-derived, all 8 chunks):
//  - arrival: VM4 placed BEFORE a barrier in P4/P8; dependent reads
//    issue after that barrier -> all waves' slices confirmed. Prologue
//    VM4 confirms chunks (0,0),(0,1) (8 of 12 loads) before first reads.
//  - WAR: chunk's last read is compiler-waited before its consuming
//    MFMA in phase c, >=1 full barrier before the re-stage at c+1/c+2.
// Barriers: 1/phase + extra in P4/P8 = 10/iter (was 16).
// =====================================================================
#define MM(a, b, c) __builtin_amdgcn_mfma_f32_16x16x32_bf16(a, b, c, 0, 0, 0)

#define ACH(bf, kh) (As + ((bf) * 2 + (kh)) * 8192)
#define BCH(bf, kh) (Bs + ((bf) * 2 + (kh)) * 8192)

#define STAGE_A(bf, kh, koff) do { \
    const unsigned short* _s = A + gAr + (koff); \
    unsigned short* _d = ACH(bf, kh) + wave * 512; \
    GLD16(_s, _d); GLD16(_s + (long)128 * K, _d + 4096); } while (0)

#define STAGE_B(bf, kh, koff) do { \
    const unsigned short* _s = B + gBr + (koff); \
    unsigned short* _d = BCH(bf, kh) + wave * 512; \
    GLD16(_s, _d); GLD16(_s + (long)128 * K, _d + 4096); } while (0)

#define LOAD_A_TO(s, bf, ks, mh) do { \
    const unsigned short* _p = ACH(bf, ks) + aBase + (mh) * 2048; \
    _Pragma("unroll") \
    for (int _m = 0; _m < 4; ++_m) aR[s][_m] = *(const short8v*)(_p + _m * 512); } while (0)

#define READ_B_TO(s, bf, ks) do { \
    const unsigned short* _p = BCH(bf, ks) + bBase; \
    _Pragma("unroll") \
    for (int _n = 0; _n < 4; ++_n) bR[s][_n] = *(const short8v*)(_p + _n * 512); } while (0)

#define MFMA16S(as, bs, mh) do { \
    __builtin_amdgcn_s_setprio(1); \
    _Pragma("unroll") \
    for (int _m = 0; _m < 4; ++_m) { \
        acc[(mh) * 4 + _m][0] = MM(aR[as][_m], bR[bs][0], acc[(mh) * 4 + _m][0]); \
        acc[(mh) * 4 + _m][1] = MM(aR[as][_m], bR[bs][1], acc[(mh) * 4 + _m][1]); \
        acc[(mh) * 4 + _m][2] = MM(aR[as][_m], bR[bs][2], acc[(mh) * 4 + _m][2]); \
        acc[(mh) * 4 + _m][3] = MM(aR[as][_m], bR[bs][3], acc[(mh) * 4 + _m][3]); \
    } \
    __builtin_amdgcn_s_setprio(0); } while (0)

#define VM4 asm volatile("s_waitcnt vmcnt(4)" ::: "memory")
#define BAR do { __builtin_amdgcn_s_barrier(); asm volatile("" ::: "memory"); } while (0)

template<int OUT_BF16, int BIAS>
__global__ __launch_bounds__(512, 2) void gemm256_kernel(
    const unsigned short* __restrict__ A,   // [M][K] bf16 bits
    const unsigned short* __restrict__ B,   // [N][K] bf16 bits
    void* __restrict__ Cv, const float* __restrict__ bias,
    int M, int N, int K) {
    __shared__ unsigned short As[4 * 8192];   // 64 KB
    __shared__ unsigned short Bs[4 * 8192];   // 64 KB

    const int tid  = threadIdx.x;
    const int wave = tid >> 6;
    const int lane = tid & 63;
    const int fr   = lane & 15;
    const int fq   = lane >> 4;

    // XCD-aware bijective swizzle (nwg % 8 == 0 for all launches)
    const int nwg = gridDim.x;
    const int bid = blockIdx.x;
    const int cpx = nwg >> 3;
    const int wg  = (bid & 7) * cpx + (bid >> 3);
    const int ntn = N >> 8;
    const long m0 = (long)(wg / ntn) << 8;
    const long n0 = (long)(wg % ntn) << 8;

    const int wwr = wave >> 2;   // 0..1  (M half)
    const int wwc = wave & 3;    // 0..3  (N quarter)

    // Stage addressing (verified): chunk [256 rows][32 k] bf16, 1024
    // 16B slots; global src slot = (si&3) ^ ((row>>1)&3).
    const int  rS  = tid >> 2;                        // rows rS and rS+128
    const int  sS  = (tid & 3) ^ ((rS >> 1) & 3);
    const long gAr = (m0 + rS) * K + sS * 8;
    const long gBr = (n0 + rS) * K + sS * 8;

    // ds_read addressing (swizzled): elem = row*32 + ((fq ^ ((row>>1)&3))*8)
    const int swz   = (fq ^ ((fr >> 1) & 3)) * 8;
    const int aBase = (wwr * 128 + fr) * 32 + swz;
    const int bBase = (wwc * 64 + fr) * 32 + swz;

    f32x4  acc[8][4] = {};
    short8v aR[2][4], bR[2][4];

    // Prologue: stage (0,0),(0,1),(1,0) = 12 loads; VM4 confirms first 8
    // -> chunks (0,0) and (0,1) resident. Then prefetch cluster-P1 frags.
    STAGE_A(0, 0, 0);  STAGE_B(0, 0, 0);
    STAGE_A(0, 1, 32); STAGE_B(0, 1, 32);
    STAGE_A(1, 0, 64); STAGE_B(1, 0, 64);
    VM4;
    BAR;
    LOAD_A_TO(1, 0, 0, 0); READ_B_TO(0, 0, 0);   // frags for P1

    const int nIter = K >> 7;   // 2 K-tiles (BK=64) per iteration
    for (int i = 0; i < nIter; ++i) {
        const int kt1off = 128 * i + 96;              // buf1.kh1 (in-bounds)
        int k3 = 128 * i + 128; if (k3 >= K) k3 -= K; // next buf0.kh0 (wrap: dead)
        int k5 = 128 * i + 160; if (k5 >= K) k5 -= K; // next buf0.kh1
        int k7 = 128 * i + 192; if (k7 >= K) k7 -= K; // next buf1.kh0

        // P1: compute (0,k0,mh0) [a1,b0]; prefetch a0 <- (0,k0,mh1)
        STAGE_A(1, 1, kt1off);
        LOAD_A_TO(0, 0, 0, 1);
        MFMA16S(1, 0, 0);
        BAR;
        // P2: compute (0,k0,mh1) [a0,b0]; prefetch a1,b1 <- (0,k1)
        STAGE_B(1, 1, kt1off);
        LOAD_A_TO(1, 0, 1, 0); READ_B_TO(1, 0, 1);
        MFMA16S(0, 0, 1);
        BAR;
        // P3: compute (0,k1,mh0) [a1,b1]; prefetch a0 <- (0,k1,mh1)
        STAGE_A(0, 0, k3);
        LOAD_A_TO(0, 0, 1, 1);
        MFMA16S(1, 1, 0);
        BAR;
        // P4: VM4+BAR (confirm (1,0),(1,1) arrival block-wide), then
        //     prefetch a1,b0 <- (1,k0); compute (0,k1,mh1) [a0,b1]
        STAGE_B(0, 0, k3);
        VM4;
        BAR;
        LOAD_A_TO(1, 1, 0, 0); READ_B_TO(0, 1, 0);
        MFMA16S(0, 1, 1);
        BAR;
        // P5: compute (1,k0,mh0) [a1,b0]; prefetch a0 <- (1,k0,mh1)
        STAGE_A(0, 1, k5);
        LOAD_A_TO(0, 1, 0, 1);
        MFMA16S(1, 0, 0);
        BAR;
        // P6: compute (1,k0,mh1) [a0,b0]; prefetch a1,b1 <- (1,k1)
        STAGE_B(0, 1, k5);
        LOAD_A_TO(1, 1, 1, 0); READ_B_TO(1, 1, 1);
        MFMA16S(0, 0, 1);
        BAR;
        // P7: compute (1,k1,mh0) [a1,b1]; prefetch a0 <- (1,k1,mh1)
        STAGE_A(1, 0, k7);
        LOAD_A_TO(0, 1, 1, 1);
        MFMA16S(1, 1, 0);
        BAR;
        // P8: VM4+BAR (confirm next (0,0),(0,1)), prefetch a1,b0 <-
        //     next-iter (0,k0); compute (1,k1,mh1) [a0,b1]
        STAGE_B(1, 0, k7);
        VM4;
        BAR;
        LOAD_A_TO(1, 0, 0, 0); READ_B_TO(0, 0, 0);
        MFMA16S(0, 1, 1);
        BAR;
    }

    // Epilogue: C/D layout col = lane&15, row = (lane>>4)*4 + j
#pragma unroll
    for (int nf = 0; nf < 4; ++nf) {
        const int col = (int)n0 + wwc * 64 + nf * 16 + fr;
        float bv = BIAS ? bias[col] : 0.0f;
#pragma unroll
        for (int mf = 0; mf < 8; ++mf) {
            f32x4 v = acc[mf][nf];
            long rowb = m0 + wwr * 128 + mf * 16 + fq * 4;
#pragma unroll
            for (int j = 0; j < 4; ++j) {
                float val = v[j] + bv;
                long off = (rowb + j) * N + col;
                if (OUT_BF16) ((unsigned short*)Cv)[off] = f2bf(val);
                else          ((float*)Cv)[off] = val;
            }
        }
    }
}

extern "C" void kernel_launch(void* const* d_in, const int* in_sizes, int n_in,
                              void* d_out, int out_size, void* d_ws, size_t ws_size,
                              hipStream_t stream) {
    const float* x    = (const float*)d_in[0];   // [4,2048,4096] = [8192][4096]
    const float* U    = (const float*)d_in[1];   // [4096][4096]
    const float* S    = (const float*)d_in[2];   // [4096]
    const float* Vt   = (const float*)d_in[3];   // [4096][4096]
    const float* eps  = (const float*)d_in[4];   // [4096]
    const float* bias = (const float*)d_in[5];   // [4096]
    float* out = (float*)d_out;                  // [8192][4096] fp32

    char* ws = (char*)d_ws;
    unsigned short* Ub  = (unsigned short*)(ws);                       // 32 MB
    unsigned short* VtT = (unsigned short*)(ws + (size_t)(32 << 20));  // 32 MB
    unsigned short* Wb  = (unsigned short*)(ws + (size_t)(64 << 20));  // 32 MB
    unsigned short* Xb  = (unsigned short*)(ws);  // 64 MB, reuses Ub+VtT after GEMM1

    // 1) Ub = bf16(U * (S+eps))            [o][r]
    prep_u_kernel<<<8192, 256, 0, stream>>>(U, S, eps, Ub);
    // 2) VtT = bf16(Vt^T)                  [k][r]
    transpose_cvt_kernel<<<dim3(64, 64), 256, 0, stream>>>(Vt, VtT);
    // 3) Wb[o][k] = Ub @ VtT^T             (NT, K=r)  -> 256 wg
    gemm256_kernel<1, 0><<<256, 512, 0, stream>>>(Ub, VtT, (void*)Wb, nullptr,
                                                  4096, 4096, 4096);
    // 4) Xb = bf16(x)                      [m][k]  (overwrites Ub/VtT — now dead)
    cvt_bf16_kernel<<<16384, 256, 0, stream>>>(x, Xb);
    // 5) out[m][o] = Xb @ Wb^T + bias      (NT, K=k)  -> 512 wg
    gemm256_kernel<0, 1><<<512, 512, 0, stream>>>(Xb, Wb, (void*)out, bias,
                                                  8192, 4096, 4096);
}